// Round 6
// baseline (1603.715 us; speedup 1.0000x reference)
//
#include <hip/hip_runtime.h>

namespace {
constexpr int B = 1024, Q = 128, P = 32, N = 128, D = 64, K = 160;

// ---------------- mean distance over cdist(x, y_pos) ----------------
__global__ __launch_bounds__(256) void k_meandist(
    const float* __restrict__ x, const float* __restrict__ y_pos,
    double* __restrict__ ws) {
  __shared__ float Yp[P][D];
  __shared__ float ysq[P];
  __shared__ float red[4];
  const int b = blockIdx.x, tid = threadIdx.x;
  const float* yb = y_pos + (size_t)b * P * D;
  for (int i = tid; i < P * D / 4; i += 256)
    reinterpret_cast<float4*>(&Yp[0][0])[i] = reinterpret_cast<const float4*>(yb)[i];
  __syncthreads();
  if (tid < P) {
    float s = 0.f;
    for (int d = 0; d < D; ++d) { float v = Yp[tid][d]; s = fmaf(v, v, s); }
    ysq[tid] = s;
  }
  __syncthreads();
  const int q = tid >> 1, ph = tid & 1;
  const float* xq = x + ((size_t)b * Q + q) * D;
  float acc[16];
#pragma unroll
  for (int j = 0; j < 16; ++j) acc[j] = 0.f;
  float xsq = 0.f;
#pragma unroll 1
  for (int d4 = 0; d4 < 16; ++d4) {
    float4 xv = reinterpret_cast<const float4*>(xq)[d4];
    xsq = fmaf(xv.x, xv.x, fmaf(xv.y, xv.y, fmaf(xv.z, xv.z, fmaf(xv.w, xv.w, xsq))));
#pragma unroll
    for (int j = 0; j < 16; ++j) {
      float4 yv = reinterpret_cast<const float4*>(&Yp[ph * 16 + j][0])[d4];
      acc[j] = fmaf(xv.x, yv.x, fmaf(xv.y, yv.y, fmaf(xv.z, yv.z, fmaf(xv.w, yv.w, acc[j]))));
    }
  }
  float dsum = 0.f;
#pragma unroll
  for (int j = 0; j < 16; ++j) {
    float d2 = xsq + ysq[ph * 16 + j] - 2.f * acc[j];
    dsum += sqrtf(fmaxf(d2, 0.f));
  }
#pragma unroll
  for (int m = 1; m < 64; m <<= 1) dsum += __shfl_xor(dsum, m);
  if ((tid & 63) == 0) red[tid >> 6] = dsum;
  __syncthreads();
  if (tid == 0)
    atomicAdd(ws, (double)(red[0] + red[1] + red[2] + red[3]));
}

// ---------------- main fused drift kernel ----------------
// 512 threads, one block per batch, ~68 KB LDS -> 2 blocks/CU (4 waves/EU).
// vs R5 (133 KB, 1 block/CU, VALUBusy 55%): the full C matrix is replaced by
// a 40-k C slab produced/consumed in 4 passes; X staged in two 16 KB chunks
// aliased into the slab region. Thread (qg,kt) owns q in [8qg,8qg+8) and
// k in {kt+32j}, so every slab is produced by ~all threads and j==4 <=> pos
// (compile-time). waves_per_eu(4,4): VGPR budget 128, live set ~95 (R2-R4
// lesson: the allocator's occupancy target dictates spills; pin it).
__global__
__attribute__((amdgpu_flat_work_group_size(512, 512)))
__attribute__((amdgpu_waves_per_eu(4, 4)))
void k_drift(
    const float* __restrict__ x, const float* __restrict__ y_pos,
    const float* __restrict__ y_neg, double* __restrict__ ws) {
  // LDS map (floats):
  //  [0,10240)      Y4  [160][16] f4, row-rotated by k (reused as merge buf)
  //  [10240,15520)  union: X4c [128][8] f4 (4096 f) / C slab [40][33] f4 (5280 f)
  //  [15520,15904)  rss [3][128]
  //  [15904,16384)  css [3][160] -> rsqrt in place
  //  [16384,16768)  uss [3][128] -> /rs in place
  //  [16768,17152)  vss [3][128] -> /rs in place
  //  [17152,17312)  ysq [160]
  //  [17312,17320)  redd (4 doubles)
  __shared__ __align__(16) float SM[17328];
  float4* Y4  = (float4*)SM;
  float4* X4c = (float4*)(SM + 10240);
  float4* C4s = (float4*)(SM + 10240);
  float* rss = SM + 15520;
  float* css = SM + 15904;
  float* uss = SM + 16384;
  float* vss = SM + 16768;
  float* ysq = SM + 17152;
  double* redd = (double*)(SM + 17312);

  const int b = blockIdx.x, tid = threadIdx.x;
  const float4* yn4 = (const float4*)(y_neg + (size_t)b * N * D);
  const float4* yp4 = (const float4*)(y_pos + (size_t)b * P * D);
  const float4* xg  = (const float4*)(x + (size_t)b * Q * D);

  // ---- stage Y (rotated) + zero reduction buffers ----
  for (int idx = tid; idx < K * 16; idx += 512) {
    int k = idx >> 4, d4 = idx & 15;
    float4 v = (k < N) ? yn4[k * 16 + d4] : yp4[(k - N) * 16 + d4];
    Y4[k * 16 + ((d4 + k) & 15)] = v;
  }
  if (tid < 384) { rss[tid] = 0.f; uss[tid] = 0.f; vss[tid] = 0.f; }
  __syncthreads();
  if (tid < K) {
    float s = 0.f;
#pragma unroll
    for (int c = 0; c < 16; ++c) {
      float4 v = Y4[tid * 16 + ((c + tid) & 15)];
      s = fmaf(v.x, v.x, fmaf(v.y, v.y, fmaf(v.z, v.z, fmaf(v.w, v.w, s))));
    }
    ysq[tid] = s;
  }

  const int qg = tid & 15, kt = tid >> 4;    // own q in [8qg,8qg+8), k = kt+32j
  const int qb = qg * 8;

  // ---- distance tiles -> zz[i][j] = exp(-dist(qb+i, kt+32j) * invt2) ----
  float zz[8][5];
  float xsq[8];
#pragma unroll
  for (int i = 0; i < 8; ++i) {
    xsq[i] = 0.f;
#pragma unroll
    for (int j = 0; j < 5; ++j) zz[i][j] = 0.f;
  }

#pragma unroll 1
  for (int ch = 0; ch < 2; ++ch) {
    __syncthreads();     // union region free (ch0: nothing; ch1: prev chunk read)
#pragma unroll
    for (int r = 0; r < 2; ++r) {
      int idx = tid + 512 * r;
      int q = idx >> 3, c = idx & 7;
      X4c[q * 8 + ((c + (q >> 3)) & 7)] = xg[q * 16 + ch * 8 + c];
    }
    __syncthreads();
#pragma unroll
    for (int d4 = 0; d4 < 8; ++d4) {
      const int rx = (d4 + qg) & 7;
      float4 xv[8];
#pragma unroll
      for (int i = 0; i < 8; ++i) xv[i] = X4c[(qb + i) * 8 + rx];
#pragma unroll
      for (int i = 0; i < 8; ++i)
        xsq[i] = fmaf(xv[i].x, xv[i].x, fmaf(xv[i].y, xv[i].y,
                 fmaf(xv[i].z, xv[i].z, fmaf(xv[i].w, xv[i].w, xsq[i]))));
      const int gd4 = ch * 8 + d4;
#pragma unroll
      for (int j = 0; j < 5; ++j) {
        const int k = kt + 32 * j;
        float4 yv = Y4[k * 16 + ((gd4 + k) & 15)];
#pragma unroll
        for (int i = 0; i < 8; ++i)
          zz[i][j] = fmaf(xv[i].x, yv.x, fmaf(xv[i].y, yv.y,
                     fmaf(xv[i].z, yv.z, fmaf(xv[i].w, yv.w, zz[i][j]))));
      }
    }
  }

  const float meand = (float)(ws[0] * (1.0 / ((double)B * Q * P)));
  const float invt2 = 1.0f / fmaxf(meand, 1e-6f);
#pragma unroll
  for (int i = 0; i < 8; ++i)
#pragma unroll
    for (int j = 0; j < 5; ++j) {
      const int k = kt + 32 * j;
      float d2 = xsq[i] + ysq[k] - 2.f * zz[i][j];
      zz[i][j] = __expf(-sqrtf(fmaxf(d2, 0.f)) * invt2);
    }

  // ---- pass 1: row sums (rss) / col sums (css) per temp ----
#pragma unroll
  for (int t = 0; t < 3; ++t) {
    float ers[8] = {0.f,0.f,0.f,0.f,0.f,0.f,0.f,0.f};
    float ecs[5] = {0.f,0.f,0.f,0.f,0.f};
#pragma unroll
    for (int i = 0; i < 8; ++i)
#pragma unroll
      for (int j = 0; j < 5; ++j) {
        float z = zz[i][j], f;
        if (t == 2) f = z;
        else if (t == 1) f = z * z;
        else { float z2 = z * z, z4 = z2 * z2; f = z4 * z4 * z2; }
        ers[i] += f; ecs[j] += f;
      }
#pragma unroll
    for (int j = 0; j < 5; ++j) {
      float v = ecs[j];
      v += __shfl_xor(v, 1); v += __shfl_xor(v, 2);
      v += __shfl_xor(v, 4); v += __shfl_xor(v, 8);
      if (qg == 0) css[t * 160 + kt + 32 * j] = v;
    }
#pragma unroll
    for (int i = 0; i < 8; ++i) {
      float v = ers[i];
      v += __shfl_xor(v, 16); v += __shfl_xor(v, 32);
      if ((kt & 3) == 0) atomicAdd(&rss[t * 128 + qb + i], v);
    }
  }
  __syncthreads();
  if (tid < 480) css[tid] = rsqrtf(css[tid]);
  __syncthreads();

  // ---- pass 2: sum_pos (uss) / sum_neg (vss) of e*ics per (temp, q) ----
#pragma unroll
  for (int t = 0; t < 3; ++t) {
    float icr[5];
#pragma unroll
    for (int j = 0; j < 5; ++j) icr[j] = css[t * 160 + kt + 32 * j];
    float uu[8] = {0.f,0.f,0.f,0.f,0.f,0.f,0.f,0.f};
    float vv[8] = {0.f,0.f,0.f,0.f,0.f,0.f,0.f,0.f};
#pragma unroll
    for (int i = 0; i < 8; ++i)
#pragma unroll
      for (int j = 0; j < 5; ++j) {
        float z = zz[i][j], f;
        if (t == 2) f = z;
        else if (t == 1) f = z * z;
        else { float z2 = z * z, z4 = z2 * z2; f = z4 * z4 * z2; }
        float a = f * icr[j];
        if (j == 4) uu[i] += a; else vv[i] += a;   // j==4 <=> k>=128 <=> pos
      }
#pragma unroll
    for (int i = 0; i < 8; ++i) {
      float u = uu[i];
      u += __shfl_xor(u, 16); u += __shfl_xor(u, 32);
      float v = vv[i];
      v += __shfl_xor(v, 16); v += __shfl_xor(v, 32);
      if ((kt & 3) == 0) {
        atomicAdd(&uss[t * 128 + qb + i], u);
        atomicAdd(&vss[t * 128 + qb + i], v);
      }
    }
  }
  __syncthreads();
  if (tid < 384) {
    float inv = 1.0f / rss[tid];
    uss[tid] *= inv;
    vss[tid] *= inv;
  }

  // ---- 4 slabs: produce combined coefficients (40 k), consume as GEMM ----
  const int qc = (tid >> 3) & 31, dc = tid & 7, kc = tid >> 8;
  float dr[4][8];
#pragma unroll
  for (int i = 0; i < 4; ++i)
#pragma unroll
    for (int n = 0; n < 8; ++n) dr[i][n] = 0.f;

#pragma unroll 1
  for (int s = 0; s < 4; ++s) {
    __syncthreads();    // slab buffer free (s=0: also covers uss/vss scaling)
#pragma unroll
    for (int j = 0; j < 5; ++j) {
      const int klocal = kt + 32 * j - 40 * s;
      if (klocal >= 0 && klocal < 40) {
        const int k = kt + 32 * j;
        const bool pos = (j == 4);
        const float ic0 = css[k], ic1 = css[160 + k], ic2 = css[320 + k];
        float c0a[8];
#pragma unroll
        for (int i = 0; i < 8; ++i) {
          const int q2 = qb + i;
          float a0 = pos ? vss[q2]       : uss[q2];
          float a1 = pos ? vss[128 + q2] : uss[128 + q2];
          float a2 = pos ? vss[256 + q2] : uss[256 + q2];
          float z = zz[i][j], z2 = z * z, z4 = z2 * z2, z10 = z4 * z4 * z2;
          float c = fmaf(z, ic2 * a2, fmaf(z2, ic1 * a1, z10 * (ic0 * a0)));
          c0a[i] = pos ? c : -c;
        }
        C4s[klocal * 33 + 2 * qg]     = make_float4(c0a[0], c0a[1], c0a[2], c0a[3]);
        C4s[klocal * 33 + 2 * qg + 1] = make_float4(c0a[4], c0a[5], c0a[6], c0a[7]);
      }
    }
    __syncthreads();
#pragma unroll 2
    for (int kl = 0; kl < 20; ++kl) {
      const int klocal = kc * 20 + kl;
      const int k = 40 * s + klocal;
      float4 ca = C4s[klocal * 33 + qc];
      float4 y0 = Y4[k * 16 + ((dc * 2 + k) & 15)];
      float4 y1 = Y4[k * 16 + ((dc * 2 + 1 + k) & 15)];
#define GACC(ii, cv)                               \
      dr[ii][0] = fmaf(cv, y0.x, dr[ii][0]);       \
      dr[ii][1] = fmaf(cv, y0.y, dr[ii][1]);       \
      dr[ii][2] = fmaf(cv, y0.z, dr[ii][2]);       \
      dr[ii][3] = fmaf(cv, y0.w, dr[ii][3]);       \
      dr[ii][4] = fmaf(cv, y1.x, dr[ii][4]);       \
      dr[ii][5] = fmaf(cv, y1.y, dr[ii][5]);       \
      dr[ii][6] = fmaf(cv, y1.z, dr[ii][6]);       \
      dr[ii][7] = fmaf(cv, y1.w, dr[ii][7]);
      GACC(0, ca.x) GACC(1, ca.y) GACC(2, ca.z) GACC(3, ca.w)
#undef GACC
    }
  }
  __syncthreads();

  // ---- merge k-halves (reuse Y space) + loss reduction ----
  float4* FB = Y4;
  if (kc == 1) {
#pragma unroll
    for (int i = 0; i < 4; ++i) {
      const int q = qc * 4 + i;
#pragma unroll
      for (int w = 0; w < 2; ++w)
        FB[q * 16 + ((dc * 2 + w + qc) & 15)] =
            make_float4(dr[i][w * 4], dr[i][w * 4 + 1], dr[i][w * 4 + 2], dr[i][w * 4 + 3]);
    }
  }
  __syncthreads();
  if (kc == 0) {
    float tot = 0.f;
#pragma unroll
    for (int i = 0; i < 4; ++i) {
      const int q = qc * 4 + i;
#pragma unroll
      for (int w = 0; w < 2; ++w) {
        float4 v = FB[q * 16 + ((dc * 2 + w + qc) & 15)];
        float a0 = dr[i][w * 4]     + v.x;
        float a1 = dr[i][w * 4 + 1] + v.y;
        float a2 = dr[i][w * 4 + 2] + v.z;
        float a3 = dr[i][w * 4 + 3] + v.w;
        tot = fmaf(a0, a0, tot);
        tot = fmaf(a1, a1, tot);
        tot = fmaf(a2, a2, tot);
        tot = fmaf(a3, a3, tot);
      }
    }
#pragma unroll
    for (int m = 1; m < 64; m <<= 1) tot += __shfl_xor(tot, m);
    if ((tid & 63) == 0) redd[tid >> 6] = (double)tot;
  }
  __syncthreads();
  if (tid == 0)
    atomicAdd(ws + 1, redd[0] + redd[1] + redd[2] + redd[3]);
}

__global__ void k_final(const double* __restrict__ ws, float* __restrict__ out) {
  out[0] = (float)(ws[1] / ((double)B * Q * D));
}

}  // namespace

extern "C" void kernel_launch(void* const* d_in, const int* in_sizes, int n_in,
                              void* d_out, int out_size, void* d_ws, size_t ws_size,
                              hipStream_t stream) {
  const float* x = (const float*)d_in[0];
  const float* y_pos = (const float*)d_in[1];
  const float* y_neg = (const float*)d_in[2];
  float* out = (float*)d_out;
  double* ws = (double*)d_ws;

  hipMemsetAsync(d_ws, 0, 2 * sizeof(double), stream);
  k_meandist<<<B, 256, 0, stream>>>(x, y_pos, ws);
  k_drift<<<B, 512, 0, stream>>>(x, y_pos, y_neg, ws);
  k_final<<<1, 1, 0, stream>>>(ws, out);
}

// Round 7
// 396.626 us; speedup vs baseline: 4.0434x; 4.0434x over previous
//
#include <hip/hip_runtime.h>

namespace {
constexpr int B = 1024, Q = 128, P = 32, N = 128, D = 64, K = 160;

// ---------------- mean distance over cdist(x, y_pos) ----------------
__global__ __launch_bounds__(256) void k_meandist(
    const float* __restrict__ x, const float* __restrict__ y_pos,
    double* __restrict__ ws) {
  __shared__ float Yp[P][D];
  __shared__ float ysq[P];
  __shared__ float red[4];
  const int b = blockIdx.x, tid = threadIdx.x;
  const float* yb = y_pos + (size_t)b * P * D;
  for (int i = tid; i < P * D / 4; i += 256)
    reinterpret_cast<float4*>(&Yp[0][0])[i] = reinterpret_cast<const float4*>(yb)[i];
  __syncthreads();
  if (tid < P) {
    float s = 0.f;
    for (int d = 0; d < D; ++d) { float v = Yp[tid][d]; s = fmaf(v, v, s); }
    ysq[tid] = s;
  }
  __syncthreads();
  const int q = tid >> 1, ph = tid & 1;
  const float* xq = x + ((size_t)b * Q + q) * D;
  float acc[16];
#pragma unroll
  for (int j = 0; j < 16; ++j) acc[j] = 0.f;
  float xsq = 0.f;
#pragma unroll 1
  for (int d4 = 0; d4 < 16; ++d4) {
    float4 xv = reinterpret_cast<const float4*>(xq)[d4];
    xsq = fmaf(xv.x, xv.x, fmaf(xv.y, xv.y, fmaf(xv.z, xv.z, fmaf(xv.w, xv.w, xsq))));
#pragma unroll
    for (int j = 0; j < 16; ++j) {
      float4 yv = reinterpret_cast<const float4*>(&Yp[ph * 16 + j][0])[d4];
      acc[j] = fmaf(xv.x, yv.x, fmaf(xv.y, yv.y, fmaf(xv.z, yv.z, fmaf(xv.w, yv.w, acc[j]))));
    }
  }
  float dsum = 0.f;
#pragma unroll
  for (int j = 0; j < 16; ++j) {
    float d2 = xsq + ysq[ph * 16 + j] - 2.f * acc[j];
    dsum += sqrtf(fmaxf(d2, 0.f));
  }
#pragma unroll
  for (int m = 1; m < 64; m <<= 1) dsum += __shfl_xor(dsum, m);
  if ((tid & 63) == 0) red[tid >> 6] = dsum;
  __syncthreads();
  if (tid == 0)
    atomicAdd(ws, (double)(red[0] + red[1] + red[2] + red[3]));
}

// ---------------- main fused drift kernel ----------------
// 512 threads, one block per batch, ~68 KB LDS.
// VGPR-allocator rule measured over R2-R6: budget = 256 / requested
// waves_per_eu  (req 4 -> 64 VGPRs -> spills; req 2 -> 128 VGPRs).
// The attribute only sets the ALLOCATION budget; runtime occupancy comes
// from resources: 128 VGPRs + 68 KB LDS -> 2 blocks/CU = 4 waves/EU actual.
// So: request (2,2), keep LDS small -> no spill AND double occupancy vs R5.
__global__
__attribute__((amdgpu_flat_work_group_size(512, 512)))
__attribute__((amdgpu_waves_per_eu(2, 2)))
void k_drift(
    const float* __restrict__ x, const float* __restrict__ y_pos,
    const float* __restrict__ y_neg, double* __restrict__ ws) {
  // LDS map (floats):
  //  [0,10240)      Y4  [160][16] f4, row-rotated by k (reused as merge buf)
  //  [10240,15520)  union: X4c [128][8] f4 (4096 f) / C slab [40][33] f4 (5280 f)
  //  [15520,15904)  rss [3][128]
  //  [15904,16384)  css [3][160] -> rsqrt in place
  //  [16384,16768)  uss [3][128] -> /rs in place
  //  [16768,17152)  vss [3][128] -> /rs in place
  //  [17152,17312)  ysq [160]
  //  [17312,17320)  redd (4 doubles)
  __shared__ __align__(16) float SM[17328];
  float4* Y4  = (float4*)SM;
  float4* X4c = (float4*)(SM + 10240);
  float4* C4s = (float4*)(SM + 10240);
  float* rss = SM + 15520;
  float* css = SM + 15904;
  float* uss = SM + 16384;
  float* vss = SM + 16768;
  float* ysq = SM + 17152;
  double* redd = (double*)(SM + 17312);

  const int b = blockIdx.x, tid = threadIdx.x;
  const float4* yn4 = (const float4*)(y_neg + (size_t)b * N * D);
  const float4* yp4 = (const float4*)(y_pos + (size_t)b * P * D);
  const float4* xg  = (const float4*)(x + (size_t)b * Q * D);

  // ---- stage Y (rotated) + zero reduction buffers ----
  for (int idx = tid; idx < K * 16; idx += 512) {
    int k = idx >> 4, d4 = idx & 15;
    float4 v = (k < N) ? yn4[k * 16 + d4] : yp4[(k - N) * 16 + d4];
    Y4[k * 16 + ((d4 + k) & 15)] = v;
  }
  if (tid < 384) { rss[tid] = 0.f; uss[tid] = 0.f; vss[tid] = 0.f; }
  __syncthreads();
  if (tid < K) {
    float s = 0.f;
#pragma unroll
    for (int c = 0; c < 16; ++c) {
      float4 v = Y4[tid * 16 + ((c + tid) & 15)];
      s = fmaf(v.x, v.x, fmaf(v.y, v.y, fmaf(v.z, v.z, fmaf(v.w, v.w, s))));
    }
    ysq[tid] = s;
  }

  const int qg = tid & 15, kt = tid >> 4;    // own q in [8qg,8qg+8), k = kt+32j
  const int qb = qg * 8;

  // ---- distance tiles -> zz[i][j] = exp(-dist(qb+i, kt+32j) * invt2) ----
  float zz[8][5];
  float xsq[8];
#pragma unroll
  for (int i = 0; i < 8; ++i) {
    xsq[i] = 0.f;
#pragma unroll
    for (int j = 0; j < 5; ++j) zz[i][j] = 0.f;
  }

#pragma unroll 1
  for (int ch = 0; ch < 2; ++ch) {
    __syncthreads();     // union region free (ch0: nothing; ch1: prev chunk read)
#pragma unroll
    for (int r = 0; r < 2; ++r) {
      int idx = tid + 512 * r;
      int q = idx >> 3, c = idx & 7;
      X4c[q * 8 + ((c + (q >> 3)) & 7)] = xg[q * 16 + ch * 8 + c];
    }
    __syncthreads();
#pragma unroll
    for (int d4 = 0; d4 < 8; ++d4) {
      const int rx = (d4 + qg) & 7;
      float4 xv[8];
#pragma unroll
      for (int i = 0; i < 8; ++i) xv[i] = X4c[(qb + i) * 8 + rx];
#pragma unroll
      for (int i = 0; i < 8; ++i)
        xsq[i] = fmaf(xv[i].x, xv[i].x, fmaf(xv[i].y, xv[i].y,
                 fmaf(xv[i].z, xv[i].z, fmaf(xv[i].w, xv[i].w, xsq[i]))));
      const int gd4 = ch * 8 + d4;
#pragma unroll
      for (int j = 0; j < 5; ++j) {
        const int k = kt + 32 * j;
        float4 yv = Y4[k * 16 + ((gd4 + k) & 15)];
#pragma unroll
        for (int i = 0; i < 8; ++i)
          zz[i][j] = fmaf(xv[i].x, yv.x, fmaf(xv[i].y, yv.y,
                     fmaf(xv[i].z, yv.z, fmaf(xv[i].w, yv.w, zz[i][j]))));
      }
    }
  }

  const float meand = (float)(ws[0] * (1.0 / ((double)B * Q * P)));
  const float invt2 = 1.0f / fmaxf(meand, 1e-6f);
#pragma unroll
  for (int i = 0; i < 8; ++i)
#pragma unroll
    for (int j = 0; j < 5; ++j) {
      const int k = kt + 32 * j;
      float d2 = xsq[i] + ysq[k] - 2.f * zz[i][j];
      zz[i][j] = __expf(-sqrtf(fmaxf(d2, 0.f)) * invt2);
    }

  // ---- pass 1: row sums (rss) / col sums (css) per temp ----
#pragma unroll
  for (int t = 0; t < 3; ++t) {
    float ers[8] = {0.f,0.f,0.f,0.f,0.f,0.f,0.f,0.f};
    float ecs[5] = {0.f,0.f,0.f,0.f,0.f};
#pragma unroll
    for (int i = 0; i < 8; ++i)
#pragma unroll
      for (int j = 0; j < 5; ++j) {
        float z = zz[i][j], f;
        if (t == 2) f = z;
        else if (t == 1) f = z * z;
        else { float z2 = z * z, z4 = z2 * z2; f = z4 * z4 * z2; }
        ers[i] += f; ecs[j] += f;
      }
#pragma unroll
    for (int j = 0; j < 5; ++j) {
      float v = ecs[j];
      v += __shfl_xor(v, 1); v += __shfl_xor(v, 2);
      v += __shfl_xor(v, 4); v += __shfl_xor(v, 8);
      if (qg == 0) css[t * 160 + kt + 32 * j] = v;
    }
#pragma unroll
    for (int i = 0; i < 8; ++i) {
      float v = ers[i];
      v += __shfl_xor(v, 16); v += __shfl_xor(v, 32);
      if ((kt & 3) == 0) atomicAdd(&rss[t * 128 + qb + i], v);
    }
  }
  __syncthreads();
  if (tid < 480) css[tid] = rsqrtf(css[tid]);
  __syncthreads();

  // ---- pass 2: sum_pos (uss) / sum_neg (vss) of e*ics per (temp, q) ----
#pragma unroll
  for (int t = 0; t < 3; ++t) {
    float icr[5];
#pragma unroll
    for (int j = 0; j < 5; ++j) icr[j] = css[t * 160 + kt + 32 * j];
    float uu[8] = {0.f,0.f,0.f,0.f,0.f,0.f,0.f,0.f};
    float vv[8] = {0.f,0.f,0.f,0.f,0.f,0.f,0.f,0.f};
#pragma unroll
    for (int i = 0; i < 8; ++i)
#pragma unroll
      for (int j = 0; j < 5; ++j) {
        float z = zz[i][j], f;
        if (t == 2) f = z;
        else if (t == 1) f = z * z;
        else { float z2 = z * z, z4 = z2 * z2; f = z4 * z4 * z2; }
        float a = f * icr[j];
        if (j == 4) uu[i] += a; else vv[i] += a;   // j==4 <=> k>=128 <=> pos
      }
#pragma unroll
    for (int i = 0; i < 8; ++i) {
      float u = uu[i];
      u += __shfl_xor(u, 16); u += __shfl_xor(u, 32);
      float v = vv[i];
      v += __shfl_xor(v, 16); v += __shfl_xor(v, 32);
      if ((kt & 3) == 0) {
        atomicAdd(&uss[t * 128 + qb + i], u);
        atomicAdd(&vss[t * 128 + qb + i], v);
      }
    }
  }
  __syncthreads();
  if (tid < 384) {
    float inv = 1.0f / rss[tid];
    uss[tid] *= inv;
    vss[tid] *= inv;
  }

  // ---- 4 slabs: produce combined coefficients (40 k), consume as GEMM ----
  const int qc = (tid >> 3) & 31, dc = tid & 7, kc = tid >> 8;
  float dr[4][8];
#pragma unroll
  for (int i = 0; i < 4; ++i)
#pragma unroll
    for (int n = 0; n < 8; ++n) dr[i][n] = 0.f;

#pragma unroll 1
  for (int s = 0; s < 4; ++s) {
    __syncthreads();    // slab buffer free (s=0: also covers uss/vss scaling)
#pragma unroll
    for (int j = 0; j < 5; ++j) {
      const int klocal = kt + 32 * j - 40 * s;
      if (klocal >= 0 && klocal < 40) {
        const int k = kt + 32 * j;
        const bool pos = (j == 4);
        const float ic0 = css[k], ic1 = css[160 + k], ic2 = css[320 + k];
        float c0a[8];
#pragma unroll
        for (int i = 0; i < 8; ++i) {
          const int q2 = qb + i;
          float a0 = pos ? vss[q2]       : uss[q2];
          float a1 = pos ? vss[128 + q2] : uss[128 + q2];
          float a2 = pos ? vss[256 + q2] : uss[256 + q2];
          float z = zz[i][j], z2 = z * z, z4 = z2 * z2, z10 = z4 * z4 * z2;
          float c = fmaf(z, ic2 * a2, fmaf(z2, ic1 * a1, z10 * (ic0 * a0)));
          c0a[i] = pos ? c : -c;
        }
        C4s[klocal * 33 + 2 * qg]     = make_float4(c0a[0], c0a[1], c0a[2], c0a[3]);
        C4s[klocal * 33 + 2 * qg + 1] = make_float4(c0a[4], c0a[5], c0a[6], c0a[7]);
      }
    }
    __syncthreads();
#pragma unroll 2
    for (int kl = 0; kl < 20; ++kl) {
      const int klocal = kc * 20 + kl;
      const int k = 40 * s + klocal;
      float4 ca = C4s[klocal * 33 + qc];
      float4 y0 = Y4[k * 16 + ((dc * 2 + k) & 15)];
      float4 y1 = Y4[k * 16 + ((dc * 2 + 1 + k) & 15)];
#define GACC(ii, cv)                               \
      dr[ii][0] = fmaf(cv, y0.x, dr[ii][0]);       \
      dr[ii][1] = fmaf(cv, y0.y, dr[ii][1]);       \
      dr[ii][2] = fmaf(cv, y0.z, dr[ii][2]);       \
      dr[ii][3] = fmaf(cv, y0.w, dr[ii][3]);       \
      dr[ii][4] = fmaf(cv, y1.x, dr[ii][4]);       \
      dr[ii][5] = fmaf(cv, y1.y, dr[ii][5]);       \
      dr[ii][6] = fmaf(cv, y1.z, dr[ii][6]);       \
      dr[ii][7] = fmaf(cv, y1.w, dr[ii][7]);
      GACC(0, ca.x) GACC(1, ca.y) GACC(2, ca.z) GACC(3, ca.w)
#undef GACC
    }
  }
  __syncthreads();

  // ---- merge k-halves (reuse Y space) + loss reduction ----
  float4* FB = Y4;
  if (kc == 1) {
#pragma unroll
    for (int i = 0; i < 4; ++i) {
      const int q = qc * 4 + i;
#pragma unroll
      for (int w = 0; w < 2; ++w)
        FB[q * 16 + ((dc * 2 + w + qc) & 15)] =
            make_float4(dr[i][w * 4], dr[i][w * 4 + 1], dr[i][w * 4 + 2], dr[i][w * 4 + 3]);
    }
  }
  __syncthreads();
  if (kc == 0) {
    float tot = 0.f;
#pragma unroll
    for (int i = 0; i < 4; ++i) {
      const int q = qc * 4 + i;
#pragma unroll
      for (int w = 0; w < 2; ++w) {
        float4 v = FB[q * 16 + ((dc * 2 + w + qc) & 15)];
        float a0 = dr[i][w * 4]     + v.x;
        float a1 = dr[i][w * 4 + 1] + v.y;
        float a2 = dr[i][w * 4 + 2] + v.z;
        float a3 = dr[i][w * 4 + 3] + v.w;
        tot = fmaf(a0, a0, tot);
        tot = fmaf(a1, a1, tot);
        tot = fmaf(a2, a2, tot);
        tot = fmaf(a3, a3, tot);
      }
    }
#pragma unroll
    for (int m = 1; m < 64; m <<= 1) tot += __shfl_xor(tot, m);
    if ((tid & 63) == 0) redd[tid >> 6] = (double)tot;
  }
  __syncthreads();
  if (tid == 0)
    atomicAdd(ws + 1, redd[0] + redd[1] + redd[2] + redd[3]);
}

__global__ void k_final(const double* __restrict__ ws, float* __restrict__ out) {
  out[0] = (float)(ws[1] / ((double)B * Q * D));
}

}  // namespace

extern "C" void kernel_launch(void* const* d_in, const int* in_sizes, int n_in,
                              void* d_out, int out_size, void* d_ws, size_t ws_size,
                              hipStream_t stream) {
  const float* x = (const float*)d_in[0];
  const float* y_pos = (const float*)d_in[1];
  const float* y_neg = (const float*)d_in[2];
  float* out = (float*)d_out;
  double* ws = (double*)d_ws;

  hipMemsetAsync(d_ws, 0, 2 * sizeof(double), stream);
  k_meandist<<<B, 256, 0, stream>>>(x, y_pos, ws);
  k_drift<<<B, 512, 0, stream>>>(x, y_pos, y_neg, ws);
  k_final<<<1, 1, 0, stream>>>(ws, out);
}

// Round 8
// 396.472 us; speedup vs baseline: 4.0450x; 1.0004x over previous
//
#include <hip/hip_runtime.h>

namespace {
constexpr int B = 1024, Q = 128, P = 32, N = 128, D = 64, K = 160;

// ---------------- mean distance over cdist(x, y_pos) ----------------
__global__ __launch_bounds__(256) void k_meandist(
    const float* __restrict__ x, const float* __restrict__ y_pos,
    double* __restrict__ ws) {
  __shared__ float Yp[P][D];
  __shared__ float ysq[P];
  __shared__ float red[4];
  const int b = blockIdx.x, tid = threadIdx.x;
  const float* yb = y_pos + (size_t)b * P * D;
  for (int i = tid; i < P * D / 4; i += 256)
    reinterpret_cast<float4*>(&Yp[0][0])[i] = reinterpret_cast<const float4*>(yb)[i];
  __syncthreads();
  if (tid < P) {
    float s = 0.f;
    for (int d = 0; d < D; ++d) { float v = Yp[tid][d]; s = fmaf(v, v, s); }
    ysq[tid] = s;
  }
  __syncthreads();
  const int q = tid >> 1, ph = tid & 1;
  const float* xq = x + ((size_t)b * Q + q) * D;
  float acc[16];
#pragma unroll
  for (int j = 0; j < 16; ++j) acc[j] = 0.f;
  float xsq = 0.f;
#pragma unroll 1
  for (int d4 = 0; d4 < 16; ++d4) {
    float4 xv = reinterpret_cast<const float4*>(xq)[d4];
    xsq = fmaf(xv.x, xv.x, fmaf(xv.y, xv.y, fmaf(xv.z, xv.z, fmaf(xv.w, xv.w, xsq))));
#pragma unroll
    for (int j = 0; j < 16; ++j) {
      float4 yv = reinterpret_cast<const float4*>(&Yp[ph * 16 + j][0])[d4];
      acc[j] = fmaf(xv.x, yv.x, fmaf(xv.y, yv.y, fmaf(xv.z, yv.z, fmaf(xv.w, yv.w, acc[j]))));
    }
  }
  float dsum = 0.f;
#pragma unroll
  for (int j = 0; j < 16; ++j) {
    float d2 = xsq + ysq[ph * 16 + j] - 2.f * acc[j];
    dsum += sqrtf(fmaxf(d2, 0.f));
  }
#pragma unroll
  for (int m = 1; m < 64; m <<= 1) dsum += __shfl_xor(dsum, m);
  if ((tid & 63) == 0) red[tid >> 6] = dsum;
  __syncthreads();
  if (tid == 0)
    atomicAdd(ws, (double)(red[0] + red[1] + red[2] + red[3]));
}

// ---------------- main fused drift kernel (producer/consumer waves) --------
// 512 threads, one block per batch, 80.9 KB LDS (2 blocks/CU possible).
// R7 lesson: fused roles need zz+dr live together (~160 regs) -> spill at the
// 128 budget. Fix: waves 0-3 = producers (hold ALL z in st[80], fed via LDS
// handoff), waves 4-7 = consumers (reuse st[0..63] as drift accumulators).
// Slabs (32 k) double-buffered: producers build s+1 while consumers GEMM s.
// waves_per_eu(2,4): min=2 keeps the 128-VGPR budget (measured rule:
// budget = 256/min); max=4 permits 2-block residency.
#define PRODUCE_COL(SL, BUFOFF, KOFF, ZOFF)                                   \
  {                                                                           \
    const int k_ = kt + (KOFF) + 32 * (SL);                                   \
    const float ic0 = css[k_], ic1 = css[160 + k_], ic2 = css[320 + k_];      \
    float c0a[8];                                                             \
    _Pragma("unroll") for (int i = 0; i < 8; ++i) {                           \
      const int q2 = qb + i;                                                  \
      float a0, a1, a2;                                                       \
      if ((SL) == 4) { a0 = vss[q2]; a1 = vss[128 + q2]; a2 = vss[256 + q2]; }\
      else           { a0 = uss[q2]; a1 = uss[128 + q2]; a2 = uss[256 + q2]; }\
      float z = st[(ZOFF) + i * 5 + (SL)];                                    \
      float z2 = z * z, z4 = z2 * z2, z10 = z4 * z4 * z2;                     \
      float c = fmaf(z, ic2 * a2, fmaf(z2, ic1 * a1, z10 * (ic0 * a0)));      \
      c0a[i] = ((SL) == 4) ? c : -c;                                          \
    }                                                                         \
    CB[(BUFOFF) + (kt + (KOFF)) * 32 + 2 * qg] =                              \
        make_float4(c0a[0], c0a[1], c0a[2], c0a[3]);                          \
    CB[(BUFOFF) + (kt + (KOFF)) * 32 + 2 * qg + 1] =                          \
        make_float4(c0a[4], c0a[5], c0a[6], c0a[7]);                          \
  }
#define PRODUCE(SL, BUFOFF)                                                   \
  { PRODUCE_COL(SL, BUFOFF, 0, 0) PRODUCE_COL(SL, BUFOFF, 16, 40) }

#define ACC(M, CV)                                                            \
  st[(M)*8 + 0] = fmaf(CV, y0.x, st[(M)*8 + 0]);                              \
  st[(M)*8 + 1] = fmaf(CV, y0.y, st[(M)*8 + 1]);                              \
  st[(M)*8 + 2] = fmaf(CV, y0.z, st[(M)*8 + 2]);                              \
  st[(M)*8 + 3] = fmaf(CV, y0.w, st[(M)*8 + 3]);                              \
  st[(M)*8 + 4] = fmaf(CV, y1.x, st[(M)*8 + 4]);                              \
  st[(M)*8 + 5] = fmaf(CV, y1.y, st[(M)*8 + 5]);                              \
  st[(M)*8 + 6] = fmaf(CV, y1.z, st[(M)*8 + 6]);                              \
  st[(M)*8 + 7] = fmaf(CV, y1.w, st[(M)*8 + 7]);
#define GEMM_SLAB(SL)                                                         \
  _Pragma("unroll") for (int i = 0; i < 16; ++i) {                            \
    const int kl = 2 * i + kc;                                                \
    const int k_ = 32 * (SL) + kl;                                            \
    float4 ca0 = CB[((SL)&1) * 1024 + kl * 32 + 2 * qgc];                     \
    float4 ca1 = CB[((SL)&1) * 1024 + kl * 32 + 2 * qgc + 1];                 \
    float4 y0 = Y4[k_ * 16 + ((2 * dc + k_) & 15)];                           \
    float4 y1 = Y4[k_ * 16 + ((2 * dc + 1 + k_) & 15)];                       \
    ACC(0, ca0.x) ACC(1, ca0.y) ACC(2, ca0.z) ACC(3, ca0.w)                   \
    ACC(4, ca1.x) ACC(5, ca1.y) ACC(6, ca1.z) ACC(7, ca1.w)                   \
  }

__global__
__attribute__((amdgpu_flat_work_group_size(512, 512)))
__attribute__((amdgpu_waves_per_eu(2, 4)))
void k_drift(
    const float* __restrict__ x, const float* __restrict__ y_pos,
    const float* __restrict__ y_neg, double* __restrict__ ws) {
  // LDS map (floats), total 20232 f = 80928 B:
  //  [0,10240)      Y4 [160][16] f4 row-rotated by k (reused as merge buf)
  //  [10240,18432)  union: X chunks (4096 f) / zz handoff (5120 f)
  //                 / 2 C-slab bufs [32][32] f4 (8192 f)
  //  [18432,18816)  rss [3][128]
  //  [18816,19296)  css [3][160] -> rsqrt in place
  //  [19296,19680)  uss [3][128] -> /rs in place
  //  [19680,20064)  vss [3][128] -> /rs in place
  //  [20064,20224)  ysq [160]
  //  [20224,20232)  redd (4 doubles)
  __shared__ __align__(16) float SM[20232];
  float4* Y4  = (float4*)SM;
  float4* X4c = (float4*)(SM + 10240);
  float4* U4  = (float4*)(SM + 10240);
  float4* CB  = (float4*)(SM + 10240);
  float* rss = SM + 18432;
  float* css = SM + 18816;
  float* uss = SM + 19296;
  float* vss = SM + 19680;
  float* ysq = SM + 20064;
  double* redd = (double*)(SM + 20224);

  const int b = blockIdx.x, tid = threadIdx.x;
  const float4* yn4 = (const float4*)(y_neg + (size_t)b * N * D);
  const float4* yp4 = (const float4*)(y_pos + (size_t)b * P * D);
  const float4* xg  = (const float4*)(x + (size_t)b * Q * D);

  // ---- stage Y (rotated) + zero sums ----
  for (int idx = tid; idx < K * 16; idx += 512) {
    int k = idx >> 4, d4 = idx & 15;
    float4 v = (k < N) ? yn4[k * 16 + d4] : yp4[(k - N) * 16 + d4];
    Y4[k * 16 + ((d4 + k) & 15)] = v;
  }
  if (tid < 384) { rss[tid] = 0.f; uss[tid] = 0.f; vss[tid] = 0.f; }
  __syncthreads();
  if (tid < K) {
    float s = 0.f;
#pragma unroll
    for (int c = 0; c < 16; ++c) {
      float4 v = Y4[tid * 16 + ((c + tid) & 15)];
      s = fmaf(v.x, v.x, fmaf(v.y, v.y, fmaf(v.z, v.z, fmaf(v.w, v.w, s))));
    }
    ysq[tid] = s;
  }

  const int qg = tid & 15, kt = tid >> 4;   // all threads: q [8qg,8qg+8), k = kt+32j
  const int qb = qg * 8;
  const bool isProd = (kt < 16);            // waves 0-3

  float st[80];   // phase A (all): z tile in st[0..39]; producers extend to 80;
                  // consumers reuse st[0..63] as drift accumulators.
#pragma unroll
  for (int f = 0; f < 40; ++f) st[f] = 0.f;
  float xsq8[8];
#pragma unroll
  for (int i = 0; i < 8; ++i) xsq8[i] = 0.f;

  // ---- dist phase (all 512 threads) ----
#pragma unroll 1
  for (int ch = 0; ch < 2; ++ch) {
    __syncthreads();
#pragma unroll
    for (int r = 0; r < 2; ++r) {
      int idx = tid + 512 * r;
      int q = idx >> 3, c = idx & 7;
      X4c[q * 8 + ((c + (q >> 3)) & 7)] = xg[q * 16 + ch * 8 + c];
    }
    __syncthreads();
#pragma unroll
    for (int d4 = 0; d4 < 8; ++d4) {
      const int rx = (d4 + qg) & 7;
      float4 xv[8];
#pragma unroll
      for (int i = 0; i < 8; ++i) xv[i] = X4c[(qb + i) * 8 + rx];
#pragma unroll
      for (int i = 0; i < 8; ++i)
        xsq8[i] = fmaf(xv[i].x, xv[i].x, fmaf(xv[i].y, xv[i].y,
                  fmaf(xv[i].z, xv[i].z, fmaf(xv[i].w, xv[i].w, xsq8[i]))));
      const int gd4 = ch * 8 + d4;
#pragma unroll
      for (int j = 0; j < 5; ++j) {
        const int k_ = kt + 32 * j;
        float4 yv = Y4[k_ * 16 + ((gd4 + k_) & 15)];
#pragma unroll
        for (int i = 0; i < 8; ++i)
          st[i * 5 + j] = fmaf(xv[i].x, yv.x, fmaf(xv[i].y, yv.y,
                          fmaf(xv[i].z, yv.z, fmaf(xv[i].w, yv.w, st[i * 5 + j]))));
      }
    }
  }
  const float meand = (float)(ws[0] * (1.0 / ((double)B * Q * P)));
  const float invt2 = 1.0f / fmaxf(meand, 1e-6f);
#pragma unroll
  for (int i = 0; i < 8; ++i)
#pragma unroll
    for (int j = 0; j < 5; ++j) {
      const int k_ = kt + 32 * j;
      float d2 = xsq8[i] + ysq[k_] - 2.f * st[i * 5 + j];
      st[i * 5 + j] = __expf(-sqrtf(fmaxf(d2, 0.f)) * invt2);
    }

  // ---- pass 1: row/col sums per temp ----
#pragma unroll
  for (int t = 0; t < 3; ++t) {
    float ers[8] = {0.f,0.f,0.f,0.f,0.f,0.f,0.f,0.f};
    float ecs[5] = {0.f,0.f,0.f,0.f,0.f};
#pragma unroll
    for (int i = 0; i < 8; ++i)
#pragma unroll
      for (int j = 0; j < 5; ++j) {
        float z = st[i * 5 + j], f;
        if (t == 2) f = z;
        else if (t == 1) f = z * z;
        else { float z2 = z * z, z4 = z2 * z2; f = z4 * z4 * z2; }
        ers[i] += f; ecs[j] += f;
      }
#pragma unroll
    for (int j = 0; j < 5; ++j) {
      float v = ecs[j];
      v += __shfl_xor(v, 1); v += __shfl_xor(v, 2);
      v += __shfl_xor(v, 4); v += __shfl_xor(v, 8);
      if (qg == 0) css[t * 160 + kt + 32 * j] = v;
    }
#pragma unroll
    for (int i = 0; i < 8; ++i) {
      float v = ers[i];
      v += __shfl_xor(v, 16); v += __shfl_xor(v, 32);
      if ((kt & 3) == 0) atomicAdd(&rss[t * 128 + qb + i], v);
    }
  }
  __syncthreads();
  if (tid < 480) css[tid] = rsqrtf(css[tid]);
  __syncthreads();

  // ---- pass 2: sum_pos (uss) / sum_neg (vss) of e*ics ----
#pragma unroll
  for (int t = 0; t < 3; ++t) {
    float icr[5];
#pragma unroll
    for (int j = 0; j < 5; ++j) icr[j] = css[t * 160 + kt + 32 * j];
    float uu[8] = {0.f,0.f,0.f,0.f,0.f,0.f,0.f,0.f};
    float vv[8] = {0.f,0.f,0.f,0.f,0.f,0.f,0.f,0.f};
#pragma unroll
    for (int i = 0; i < 8; ++i)
#pragma unroll
      for (int j = 0; j < 5; ++j) {
        float z = st[i * 5 + j], f;
        if (t == 2) f = z;
        else if (t == 1) f = z * z;
        else { float z2 = z * z, z4 = z2 * z2; f = z4 * z4 * z2; }
        float a = f * icr[j];
        if (j == 4) uu[i] += a; else vv[i] += a;   // j==4 <=> k>=128 <=> pos
      }
#pragma unroll
    for (int i = 0; i < 8; ++i) {
      float u = uu[i];
      u += __shfl_xor(u, 16); u += __shfl_xor(u, 32);
      float v = vv[i];
      v += __shfl_xor(v, 16); v += __shfl_xor(v, 32);
      if ((kt & 3) == 0) {
        atomicAdd(&uss[t * 128 + qb + i], u);
        atomicAdd(&vss[t * 128 + qb + i], v);
      }
    }
  }
  __syncthreads();
  if (tid < 384) {
    float inv = 1.0f / rss[tid];
    uss[tid] *= inv;
    vss[tid] *= inv;
  }
  __syncthreads();

  // ---- zz handoff: consumer (kt>=16) z -> producer partner (kt-16) ----
#pragma unroll
  for (int r = 0; r < 2; ++r) {
    if (!isProd && ((kt - 16) >> 3) == r) {
      const int base = ((kt - 16 - 8 * r) * 16 + qg) * 10;
#pragma unroll
      for (int f = 0; f < 10; ++f)
        U4[base + f] = make_float4(st[4*f], st[4*f+1], st[4*f+2], st[4*f+3]);
    }
    __syncthreads();
    if (isProd && (kt >> 3) == r) {
      const int base = ((kt - 8 * r) * 16 + qg) * 10;
#pragma unroll
      for (int f = 0; f < 10; ++f) {
        float4 v = U4[base + f];
        st[40 + 4*f] = v.x; st[40 + 4*f + 1] = v.y;
        st[40 + 4*f + 2] = v.z; st[40 + 4*f + 3] = v.w;
      }
    }
    __syncthreads();
  }

  // consumers: repurpose st[0..63] as drift accumulators
  const int tid2 = tid - 256;
  const int dc = tid2 & 7, qgc = (tid2 >> 3) & 15, kc = (tid2 >> 7) & 1;
  if (!isProd) {
#pragma unroll
    for (int f = 0; f < 64; ++f) st[f] = 0.f;
  }

  // ---- pipelined slab loop: produce s+1 while GEMM s ----
  if (isProd) { PRODUCE(0, 0) }
  __syncthreads();
  if (isProd) { PRODUCE(1, 1024) }
  if (!isProd) { GEMM_SLAB(0) }
  __syncthreads();
  if (isProd) { PRODUCE(2, 0) }
  if (!isProd) { GEMM_SLAB(1) }
  __syncthreads();
  if (isProd) { PRODUCE(3, 1024) }
  if (!isProd) { GEMM_SLAB(2) }
  __syncthreads();
  if (isProd) { PRODUCE(4, 0) }
  if (!isProd) { GEMM_SLAB(3) }
  __syncthreads();
  if (!isProd) { GEMM_SLAB(4) }
  __syncthreads();

  // ---- merge kc halves (reuse Y region) + loss ----
  float4* FB = Y4;
  if (!isProd && kc == 1) {
#pragma unroll
    for (int m = 0; m < 8; ++m) {
      const int q = qgc * 8 + m;
      FB[q * 16 + ((2 * dc + q) & 15)] =
          make_float4(st[m*8+0], st[m*8+1], st[m*8+2], st[m*8+3]);
      FB[q * 16 + ((2 * dc + 1 + q) & 15)] =
          make_float4(st[m*8+4], st[m*8+5], st[m*8+6], st[m*8+7]);
    }
  }
  __syncthreads();
  if (!isProd && kc == 0) {
    float tot = 0.f;
#pragma unroll
    for (int m = 0; m < 8; ++m) {
      const int q = qgc * 8 + m;
      float4 v0 = FB[q * 16 + ((2 * dc + q) & 15)];
      float4 v1 = FB[q * 16 + ((2 * dc + 1 + q) & 15)];
      float a0 = st[m*8+0] + v0.x, a1 = st[m*8+1] + v0.y;
      float a2 = st[m*8+2] + v0.z, a3 = st[m*8+3] + v0.w;
      float a4 = st[m*8+4] + v1.x, a5 = st[m*8+5] + v1.y;
      float a6 = st[m*8+6] + v1.z, a7 = st[m*8+7] + v1.w;
      tot = fmaf(a0, a0, tot); tot = fmaf(a1, a1, tot);
      tot = fmaf(a2, a2, tot); tot = fmaf(a3, a3, tot);
      tot = fmaf(a4, a4, tot); tot = fmaf(a5, a5, tot);
      tot = fmaf(a6, a6, tot); tot = fmaf(a7, a7, tot);
    }
#pragma unroll
    for (int m = 1; m < 64; m <<= 1) tot += __shfl_xor(tot, m);
    if ((tid & 63) == 0) redd[(tid >> 6) - 4] = (double)tot;
  }
  __syncthreads();
  if (tid == 0) atomicAdd(ws + 1, redd[0] + redd[1]);
}

__global__ void k_final(const double* __restrict__ ws, float* __restrict__ out) {
  out[0] = (float)(ws[1] / ((double)B * Q * D));
}

}  // namespace

extern "C" void kernel_launch(void* const* d_in, const int* in_sizes, int n_in,
                              void* d_out, int out_size, void* d_ws, size_t ws_size,
                              hipStream_t stream) {
  const float* x = (const float*)d_in[0];
  const float* y_pos = (const float*)d_in[1];
  const float* y_neg = (const float*)d_in[2];
  float* out = (float*)d_out;
  double* ws = (double*)d_ws;

  hipMemsetAsync(d_ws, 0, 2 * sizeof(double), stream);
  k_meandist<<<B, 256, 0, stream>>>(x, y_pos, ws);
  k_drift<<<B, 512, 0, stream>>>(x, y_pos, y_neg, ws);
  k_final<<<1, 1, 0, stream>>>(ws, out);
}